// Round 1
// baseline (838.697 us; speedup 1.0000x reference)
//
#include <hip/hip_runtime.h>
#include <hip/hip_bf16.h>
#include <math.h>

// ChromaticTransportEvaluator: srgb->oklab, per-image-set minmax, 8^3 histogram
// per 16x16 patch, 20-iter Sinkhorn between ref/tgt hists (shared avg grid
// cost), EMD per patch, 16x bilinear upsample.
//
// B=4, H=W=256, PATCH=16 -> P=1024 patches, N=512 bins, ITERS=20, REG=0.1,
// EPS=1e-6. K is symmetric (Euclidean cdist) so u@K.T and v@K are the same
// matvec. Patch mass is exactly 256 -> hr=count/256, empty mask never fires.

#define NPX_IMG   262144          // 4*256*256 pixels per image-set
#define LAB_STRIDE 786432         // 4*3*256*256 floats per image-set

__device__ __forceinline__ unsigned enc_f(float f) {
    unsigned u = __float_as_uint(f);
    return (u & 0x80000000u) ? ~u : (u | 0x80000000u);
}
__device__ __forceinline__ float dec_f(unsigned k) {
    unsigned u = (k & 0x80000000u) ? (k ^ 0x80000000u) : ~k;
    return __uint_as_float(u);
}

__device__ __forceinline__ float s2lin(float x) {
    x = fminf(fmaxf(x, 0.f), 1.f);
    return (x <= 0.04045f) ? (x / 12.92f)
                           : powf(fmaxf((x + 0.055f) / 1.055f, 0.f), 2.4f);
}

__device__ __forceinline__ void lohi_img(const unsigned* mm, int img,
                                         float lo[3], float hi[3]) {
    for (int c = 0; c < 3; ++c) {
        float mn = dec_f(mm[img * 6 + c * 2 + 0]);
        float mx = dec_f(mm[img * 6 + c * 2 + 1]);
        float l = mn - 0.01f, h = mx + 0.01f;
        if (h - l < 1e-4f) { l -= 0.05f; h += 0.05f; }
        lo[c] = l; hi[c] = h;
    }
}

__global__ void init_minmax_kernel(unsigned* mm) {
    int t = threadIdx.x;
    if (t < 12) mm[t] = (t & 1) ? 0u : 0xFFFFFFFFu;
}

// 1024 blocks x 256 threads, 2 px/thread. Blocks 0..511 -> ref, 512..1023 -> tgt.
__global__ __launch_bounds__(256) void oklab_minmax_kernel(
        const float* __restrict__ ref, const float* __restrict__ tgt,
        float* __restrict__ lab, unsigned* __restrict__ mm) {
    int blk = blockIdx.x;
    int img = blk >> 9;
    const float* src = img ? tgt : ref;
    float* dst = lab + img * LAB_STRIDE;

    __shared__ unsigned smin[3], smax[3];
    if (threadIdx.x < 3) { smin[threadIdx.x] = 0xFFFFFFFFu; smax[threadIdx.x] = 0u; }
    __syncthreads();

    float fmn[3] = {3.4e38f, 3.4e38f, 3.4e38f};
    float fmx[3] = {-3.4e38f, -3.4e38f, -3.4e38f};

    int base = (blk & 511) * 512;
    for (int k = 0; k < 2; ++k) {
        int px = base + k * 256 + threadIdx.x;   // 0..262143
        int bi = px >> 16;
        int rem = px & 65535;
        float r = s2lin(src[(bi * 3 + 0) * 65536 + rem]);
        float g = s2lin(src[(bi * 3 + 1) * 65536 + rem]);
        float b = s2lin(src[(bi * 3 + 2) * 65536 + rem]);
        float l0 = fmaxf(0.4122214708f * r + 0.5363325363f * g + 0.0514459929f * b, 0.f);
        float l1 = fmaxf(0.2119034982f * r + 0.6806995451f * g + 0.1073969566f * b, 0.f);
        float l2 = fmaxf(0.0883024619f * r + 0.2817188376f * g + 0.6299787005f * b, 0.f);
        // sign(lms) in {0,1}: exact 0 stays 0
        float g0 = (l0 > 0.f) ? cbrtf(fmaxf(l0, 1e-12f)) : 0.f;
        float g1 = (l1 > 0.f) ? cbrtf(fmaxf(l1, 1e-12f)) : 0.f;
        float g2 = (l2 > 0.f) ? cbrtf(fmaxf(l2, 1e-12f)) : 0.f;
        float L = 0.2104542553f * g0 + 0.793617785f * g1 - 0.0040720468f * g2;
        float A = 1.9779984951f * g0 - 2.428592205f * g1 + 0.4505937099f * g2;
        float Bv = 0.0259040371f * g0 + 0.7827717662f * g1 - 0.808675766f * g2;
        dst[(bi * 3 + 0) * 65536 + rem] = L;
        dst[(bi * 3 + 1) * 65536 + rem] = A;
        dst[(bi * 3 + 2) * 65536 + rem] = Bv;
        fmn[0] = fminf(fmn[0], L); fmx[0] = fmaxf(fmx[0], L);
        fmn[1] = fminf(fmn[1], A); fmx[1] = fmaxf(fmx[1], A);
        fmn[2] = fminf(fmn[2], Bv); fmx[2] = fmaxf(fmx[2], Bv);
    }
    for (int c = 0; c < 3; ++c) {
        atomicMin(&smin[c], enc_f(fmn[c]));
        atomicMax(&smax[c], enc_f(fmx[c]));
    }
    __syncthreads();
    if (threadIdx.x < 3) {
        atomicMin(&mm[img * 6 + threadIdx.x * 2 + 0], smin[threadIdx.x]);
        atomicMax(&mm[img * 6 + threadIdx.x * 2 + 1], smax[threadIdx.x]);
    }
}

// 512 blocks (one row i) x 256 threads (2 cols each). K = exp(-cost/0.1), Kc = K*cost
__global__ __launch_bounds__(256) void build_k_kernel(
        const unsigned* __restrict__ mm, float* __restrict__ Km, float* __restrict__ Kc) {
    float lor[3], hir[3], lot[3], hit[3];
    lohi_img(mm, 0, lor, hir);
    lohi_img(mm, 1, lot, hit);
    float cen[3][8];
    for (int c = 0; c < 3; ++c)
        for (int k = 0; k < 8; ++k) {
            float t = (k + 0.5f) * 0.125f;
            float cr = lor[c] + (hir[c] - lor[c]) * t;
            float ct = lot[c] + (hit[c] - lot[c]) * t;
            cen[c][k] = 0.5f * (cr + ct);
        }
    int i = blockIdx.x;
    float a0 = cen[0][i >> 6], a1 = cen[1][(i >> 3) & 7], a2 = cen[2][i & 7];
    for (int j = threadIdx.x; j < 512; j += 256) {
        float d0 = a0 - cen[0][j >> 6];
        float d1 = a1 - cen[1][(j >> 3) & 7];
        float d2 = a2 - cen[2][j & 7];
        float dd = d0 * d0 + d1 * d1 + d2 * d2;
        float cost = (dd > 0.f) ? sqrtf(dd) : 0.f;
        float kv = expf(-cost / 0.1f);
        Km[i * 512 + j] = kv;
        Kc[i * 512 + j] = kv * cost;
    }
}

// 2048 blocks: img = blk>>10, patch = blk&1023. 256 threads = 256 pixels.
__global__ __launch_bounds__(256) void hist_kernel(
        const float* __restrict__ lab, const unsigned* __restrict__ mm,
        float* __restrict__ hr, float* __restrict__ ht, float* __restrict__ u) {
    int blk = blockIdx.x;
    int img = blk >> 10;
    int p = blk & 1023;
    float lo[3], hi[3];
    lohi_img(mm, img, lo, hi);
    float cen[3][8];
    for (int c = 0; c < 3; ++c)
        for (int k = 0; k < 8; ++k)
            cen[c][k] = lo[c] + (hi[c] - lo[c]) * ((k + 0.5f) * 0.125f);

    __shared__ unsigned hcnt[512];
    hcnt[threadIdx.x] = 0u;
    hcnt[threadIdx.x + 256] = 0u;
    __syncthreads();

    int b = p >> 8, ph = (p >> 4) & 15, pw = p & 15;
    int y = threadIdx.x >> 4, x = threadIdx.x & 15;
    int rem = (ph * 16 + y) * 256 + (pw * 16 + x);
    const float* lb = lab + img * LAB_STRIDE;
    int kidx[3];
    for (int c = 0; c < 3; ++c) {
        float vv = lb[(b * 3 + c) * 65536 + rem];
        int best = 0; float bd = 3.4e38f;
        for (int k = 0; k < 8; ++k) {
            float d = vv - cen[c][k];
            float dd = d * d;
            if (dd < bd) { bd = dd; best = k; }
        }
        kidx[c] = best;
    }
    atomicAdd(&hcnt[kidx[0] * 64 + kidx[1] * 8 + kidx[2]], 1u);
    __syncthreads();

    float* dst = img ? ht : hr;
    dst[p * 512 + threadIdx.x] = (float)hcnt[threadIdx.x] * (1.f / 256.f);
    dst[p * 512 + threadIdx.x + 256] = (float)hcnt[threadIdx.x + 256] * (1.f / 256.f);
    if (!img) {
        u[p * 512 + threadIdx.x] = 1.f;
        u[p * 512 + threadIdx.x + 256] = 1.f;
    }
}

// dst[p][j] = hist[p][j] / (sum_i src[p][i] * K[i][j] + 1e-6)
// grid (32 p-tiles, 8 j-tiles), 256 threads, 32x64 tile, 2x4 microtile.
__global__ __launch_bounds__(256) void matvec_div_kernel(
        const float* __restrict__ src, const float* __restrict__ Km,
        const float* __restrict__ hist, float* __restrict__ dst) {
    __shared__ __align__(16) float Ks[64][68];
    __shared__ float Ss[64][33];
    int p0 = blockIdx.x * 32;
    int j0 = blockIdx.y * 64;
    int tid = threadIdx.x;
    int jl = tid & 63;
    int rl = tid >> 6;       // 0..3
    int jq = (tid & 15) * 4; // j_local base
    int pb = (tid >> 4) * 2; // p_local base
    float acc[2][4] = {{0.f, 0.f, 0.f, 0.f}, {0.f, 0.f, 0.f, 0.f}};

    for (int ic = 0; ic < 512; ic += 64) {
        #pragma unroll
        for (int r = 0; r < 16; ++r) {
            int row = rl + r * 4;
            Ks[row][jl] = Km[(ic + row) * 512 + j0 + jl];
        }
        #pragma unroll
        for (int r = 0; r < 8; ++r) {
            int pl = rl + r * 4;
            Ss[jl][pl] = src[(p0 + pl) * 512 + ic + jl];
        }
        __syncthreads();
        #pragma unroll
        for (int i = 0; i < 64; ++i) {
            float4 kv = *(const float4*)&Ks[i][jq];
            float s0 = Ss[i][pb];
            float s1 = Ss[i][pb + 1];
            acc[0][0] += s0 * kv.x; acc[0][1] += s0 * kv.y;
            acc[0][2] += s0 * kv.z; acc[0][3] += s0 * kv.w;
            acc[1][0] += s1 * kv.x; acc[1][1] += s1 * kv.y;
            acc[1][2] += s1 * kv.z; acc[1][3] += s1 * kv.w;
        }
        __syncthreads();
    }
    #pragma unroll
    for (int pp = 0; pp < 2; ++pp)
        #pragma unroll
        for (int jj = 0; jj < 4; ++jj) {
            int idx = (p0 + pb + pp) * 512 + j0 + jq + jj;
            dst[idx] = hist[idx] / (acc[pp][jj] + 1e-6f);
        }
}

// emd[p] = sum_j (sum_i Kc[i][j] u[p][i]) * v[p][j]   (Kc symmetric)
__global__ __launch_bounds__(256) void emd_kernel(
        const float* __restrict__ u, const float* __restrict__ v,
        const float* __restrict__ Kc, float* __restrict__ emd) {
    int p = blockIdx.x;
    __shared__ float us[512];
    __shared__ float red[256];
    us[threadIdx.x] = u[p * 512 + threadIdx.x];
    us[threadIdx.x + 256] = u[p * 512 + threadIdx.x + 256];
    __syncthreads();
    int j0 = threadIdx.x, j1 = threadIdx.x + 256;
    float a0 = 0.f, a1 = 0.f;
    for (int i = 0; i < 512; ++i) {
        float ui = us[i];
        a0 += Kc[i * 512 + j0] * ui;
        a1 += Kc[i * 512 + j1] * ui;
    }
    float part = a0 * v[p * 512 + j0] + a1 * v[p * 512 + j1];
    red[threadIdx.x] = part;
    __syncthreads();
    for (int s = 128; s > 0; s >>= 1) {
        if (threadIdx.x < s) red[threadIdx.x] += red[threadIdx.x + s];
        __syncthreads();
    }
    if (threadIdx.x == 0) {
        float e = red[0];
        if (!isfinite(e)) e = 0.f;   // nan_to_num
        emd[p] = e;
    }
}

// (4,1,16,16) -> (4,1,256,256), half-pixel bilinear, edge clamp
__global__ __launch_bounds__(256) void upsample_kernel(
        const float* __restrict__ emd, float* __restrict__ out) {
    int idx = blockIdx.x * 256 + threadIdx.x;   // 0..262143
    int b = idx >> 16;
    int rem = idx & 65535;
    int y = rem >> 8, x = rem & 255;
    float sy = (y + 0.5f) * 0.0625f - 0.5f;
    float sx = (x + 0.5f) * 0.0625f - 0.5f;
    float fy0 = floorf(sy), fx0 = floorf(sx);
    float fy = sy - fy0, fx = sx - fx0;
    int y0 = (int)fy0, x0 = (int)fx0;
    int y0c = min(max(y0, 0), 15), y1c = min(max(y0 + 1, 0), 15);
    int x0c = min(max(x0, 0), 15), x1c = min(max(x0 + 1, 0), 15);
    const float* e = emd + b * 256;
    float v00 = e[y0c * 16 + x0c], v01 = e[y0c * 16 + x1c];
    float v10 = e[y1c * 16 + x0c], v11 = e[y1c * 16 + x1c];
    out[idx] = (1.f - fy) * ((1.f - fx) * v00 + fx * v01)
             + fy * ((1.f - fx) * v10 + fx * v11);
}

extern "C" void kernel_launch(void* const* d_in, const int* in_sizes, int n_in,
                              void* d_out, int out_size, void* d_ws, size_t ws_size,
                              hipStream_t stream) {
    const float* ref = (const float*)d_in[0];
    const float* tgt = (const float*)d_in[1];
    float* out = (float*)d_out;

    float* lab = (float*)d_ws;                       // 2*786432
    unsigned* mm = (unsigned*)(lab + 2 * LAB_STRIDE); // 16 (12 used)
    float* Km = (float*)(mm + 16);                    // 262144
    float* Kc = Km + 262144;                          // 262144
    float* hr = Kc + 262144;                          // 524288
    float* ht = hr + 524288;                          // 524288
    float* u  = ht + 524288;                          // 524288
    float* v  = u + 524288;                           // 524288
    float* emd = v + 524288;                          // 1024

    init_minmax_kernel<<<1, 16, 0, stream>>>(mm);
    oklab_minmax_kernel<<<1024, 256, 0, stream>>>(ref, tgt, lab, mm);
    build_k_kernel<<<512, 256, 0, stream>>>(mm, Km, Kc);
    hist_kernel<<<2048, 256, 0, stream>>>(lab, mm, hr, ht, u);

    for (int it = 0; it < 20; ++it) {
        matvec_div_kernel<<<dim3(32, 8), 256, 0, stream>>>(u, Km, ht, v);
        matvec_div_kernel<<<dim3(32, 8), 256, 0, stream>>>(v, Km, hr, u);
    }
    emd_kernel<<<1024, 256, 0, stream>>>(u, v, Kc, emd);
    upsample_kernel<<<1024, 256, 0, stream>>>(emd, out);
}

// Round 3
// 439.541 us; speedup vs baseline: 1.9081x; 1.9081x over previous
//
#include <hip/hip_runtime.h>
#include <hip/hip_bf16.h>

// ChromaticTransportEvaluator — round 3 (round-2 design, compile fix).
//  * __exp2f/__log2f collide with glibc-reserved names in -x hip mode ->
//    use raw __builtin_amdgcn_exp2f / __builtin_amdgcn_logf (v_exp_f32 /
//    v_log_f32, hardware exp2/log2).
//  * Sinkhorn matvecs on bf16 MFMA with hi/lo split (3 MFMA terms,
//    rel err ~2^-16). K packed ONCE into B-fragment order; fragments load
//    straight from L2 via dwordx4 — no LDS in the GEMM.
//  * EMD -> same MFMA GEMM over Kc with per-block reduction + atomics.
//
// mfma_f32_16x16x32_bf16 layouts (guide §3, m89-verified):
//   A[m][k]: m = lane&15, k = (lane>>4)*8 + reg   (8 contiguous k -> 16B load)
//   B[k][n]: n = lane&15, k = (lane>>4)*8 + reg   (mirror)
//   C/D:     col = lane&15, row = (lane>>4)*4 + reg

#define LAB_STRIDE 786432         // 4*3*256*256 floats per image-set

typedef __attribute__((ext_vector_type(8))) short short8;
typedef __attribute__((ext_vector_type(4))) float floatx4;

__device__ __forceinline__ float hw_exp2(float x) { return __builtin_amdgcn_exp2f(x); }
__device__ __forceinline__ float hw_log2(float x) { return __builtin_amdgcn_logf(x); }

__device__ __forceinline__ unsigned enc_f(float f) {
    unsigned u = __float_as_uint(f);
    return (u & 0x80000000u) ? ~u : (u | 0x80000000u);
}
__device__ __forceinline__ float dec_f(unsigned k) {
    unsigned u = (k & 0x80000000u) ? (k ^ 0x80000000u) : ~k;
    return __uint_as_float(u);
}

__device__ __forceinline__ float s2lin(float x) {
    x = fminf(fmaxf(x, 0.f), 1.f);
    return (x <= 0.04045f) ? (x * (1.f / 12.92f))
                           : hw_exp2(2.4f * hw_log2((x + 0.055f) * (1.f / 1.055f)));
}

__device__ __forceinline__ float cbrt_fast(float l) {
    return hw_exp2(0.33333333333f * hw_log2(fmaxf(l, 1e-12f)));
}

__device__ __forceinline__ void lohi_img(const unsigned* mm, int img,
                                         float lo[3], float hi[3]) {
    for (int c = 0; c < 3; ++c) {
        float mn = dec_f(mm[img * 6 + c * 2 + 0]);
        float mx = dec_f(mm[img * 6 + c * 2 + 1]);
        float l = mn - 0.01f, h = mx + 0.01f;
        if (h - l < 1e-4f) { l -= 0.05f; h += 0.05f; }
        lo[c] = l; hi[c] = h;
    }
}

// bf16 RNE split helpers
__device__ __forceinline__ unsigned bf16_rne(float f) {
    unsigned u = __float_as_uint(f);
    return (u + 0x7FFFu + ((u >> 16) & 1u)) >> 16;
}
__device__ __forceinline__ float bf16_to_f(unsigned short b) {
    return __uint_as_float(((unsigned)b) << 16);
}

__global__ void init_kernel(unsigned* mm, float* emd) {
    int t = threadIdx.x;              // 1024 threads
    if (t < 12) mm[t] = (t & 1) ? 0u : 0xFFFFFFFFu;
    emd[t] = 0.f;
}

// 1024 blocks x 256 threads, 2 px/thread. Blocks 0..511 -> ref, 512..1023 -> tgt.
__global__ __launch_bounds__(256) void oklab_minmax_kernel(
        const float* __restrict__ ref, const float* __restrict__ tgt,
        float* __restrict__ lab, unsigned* __restrict__ mm) {
    int blk = blockIdx.x;
    int img = blk >> 9;
    const float* src = img ? tgt : ref;
    float* dst = lab + img * LAB_STRIDE;

    __shared__ unsigned smin[3], smax[3];
    if (threadIdx.x < 3) { smin[threadIdx.x] = 0xFFFFFFFFu; smax[threadIdx.x] = 0u; }
    __syncthreads();

    float fmn[3] = {3.4e38f, 3.4e38f, 3.4e38f};
    float fmx[3] = {-3.4e38f, -3.4e38f, -3.4e38f};

    int base = (blk & 511) * 512;
    for (int k = 0; k < 2; ++k) {
        int px = base + k * 256 + threadIdx.x;   // 0..262143
        int bi = px >> 16;
        int rem = px & 65535;
        float r = s2lin(src[(bi * 3 + 0) * 65536 + rem]);
        float g = s2lin(src[(bi * 3 + 1) * 65536 + rem]);
        float b = s2lin(src[(bi * 3 + 2) * 65536 + rem]);
        float l0 = fmaxf(0.4122214708f * r + 0.5363325363f * g + 0.0514459929f * b, 0.f);
        float l1 = fmaxf(0.2119034982f * r + 0.6806995451f * g + 0.1073969566f * b, 0.f);
        float l2 = fmaxf(0.0883024619f * r + 0.2817188376f * g + 0.6299787005f * b, 0.f);
        float g0 = (l0 > 0.f) ? cbrt_fast(l0) : 0.f;
        float g1 = (l1 > 0.f) ? cbrt_fast(l1) : 0.f;
        float g2 = (l2 > 0.f) ? cbrt_fast(l2) : 0.f;
        float L = 0.2104542553f * g0 + 0.793617785f * g1 - 0.0040720468f * g2;
        float A = 1.9779984951f * g0 - 2.428592205f * g1 + 0.4505937099f * g2;
        float Bv = 0.0259040371f * g0 + 0.7827717662f * g1 - 0.808675766f * g2;
        dst[(bi * 3 + 0) * 65536 + rem] = L;
        dst[(bi * 3 + 1) * 65536 + rem] = A;
        dst[(bi * 3 + 2) * 65536 + rem] = Bv;
        fmn[0] = fminf(fmn[0], L); fmx[0] = fmaxf(fmx[0], L);
        fmn[1] = fminf(fmn[1], A); fmx[1] = fmaxf(fmx[1], A);
        fmn[2] = fminf(fmn[2], Bv); fmx[2] = fmaxf(fmx[2], Bv);
    }
    for (int c = 0; c < 3; ++c) {
        atomicMin(&smin[c], enc_f(fmn[c]));
        atomicMax(&smax[c], enc_f(fmx[c]));
    }
    __syncthreads();
    if (threadIdx.x < 3) {
        atomicMin(&mm[img * 6 + threadIdx.x * 2 + 0], smin[threadIdx.x]);
        atomicMax(&mm[img * 6 + threadIdx.x * 2 + 1], smax[threadIdx.x]);
    }
}

// Pack K=exp(-cost/0.1) and Kc=K*cost into hi/lo bf16, B-fragment order.
// grid (32 jtiles, 16 kchunks) x 64 threads. Element for (jt,kc,lane,reg):
//   k = kc*32 + (lane>>4)*8 + reg, n = jt*16 + (lane&15)
//   stored at [((jt*16+kc)*64 + lane)*8 + reg]
__global__ __launch_bounds__(64) void pack_k_kernel(
        const unsigned* __restrict__ mm,
        short* __restrict__ kmh, short* __restrict__ kml,
        short* __restrict__ kch, short* __restrict__ kcl) {
    float lor[3], hir[3], lot[3], hit[3];
    lohi_img(mm, 0, lor, hir);
    lohi_img(mm, 1, lot, hit);
    float cen[3][8];
    for (int c = 0; c < 3; ++c)
        for (int k = 0; k < 8; ++k) {
            float t = (k + 0.5f) * 0.125f;
            cen[c][k] = 0.5f * ((lor[c] + (hir[c] - lor[c]) * t)
                              + (lot[c] + (hit[c] - lot[c]) * t));
        }
    int jt = blockIdx.x, kc = blockIdx.y;
    int lane = threadIdx.x;
    int n = jt * 16 + (lane & 15);
    int kb = kc * 32 + (lane >> 4) * 8;
    float n0 = cen[0][n >> 6], n1 = cen[1][(n >> 3) & 7], n2 = cen[2][n & 7];
    short8 vmh, vml, vch, vcl;
    #pragma unroll
    for (int r = 0; r < 8; ++r) {
        int k = kb + r;
        float d0 = cen[0][k >> 6] - n0;
        float d1 = cen[1][(k >> 3) & 7] - n1;
        float d2 = cen[2][k & 7] - n2;
        float dd = d0 * d0 + d1 * d1 + d2 * d2;
        float cost = (dd > 0.f) ? __fsqrt_rn(dd) : 0.f;
        // exp(-10*cost) = exp2(-10*cost*log2(e))
        float kv = hw_exp2(-cost * 14.426950408889634f);
        float cv = kv * cost;
        unsigned h = bf16_rne(kv);
        float hf = bf16_to_f((unsigned short)h);
        unsigned l = bf16_rne(kv - hf);
        vmh[r] = (short)h; vml[r] = (short)l;
        h = bf16_rne(cv);
        hf = bf16_to_f((unsigned short)h);
        l = bf16_rne(cv - hf);
        vch[r] = (short)h; vcl[r] = (short)l;
    }
    int base = ((jt * 16 + kc) * 64 + lane) * 8;
    *(short8*)(kmh + base) = vmh;
    *(short8*)(kml + base) = vml;
    *(short8*)(kch + base) = vch;
    *(short8*)(kcl + base) = vcl;
}

// 2048 blocks: img = blk>>10, patch = blk&1023. 256 threads = 256 pixels.
__global__ __launch_bounds__(256) void hist_kernel(
        const float* __restrict__ lab, const unsigned* __restrict__ mm,
        float* __restrict__ hr, float* __restrict__ ht,
        short* __restrict__ uh, short* __restrict__ ul) {
    int blk = blockIdx.x;
    int img = blk >> 10;
    int p = blk & 1023;
    float lo[3], hi[3];
    lohi_img(mm, img, lo, hi);
    float cen[3][8];
    for (int c = 0; c < 3; ++c)
        for (int k = 0; k < 8; ++k)
            cen[c][k] = lo[c] + (hi[c] - lo[c]) * ((k + 0.5f) * 0.125f);

    __shared__ unsigned hcnt[512];
    hcnt[threadIdx.x] = 0u;
    hcnt[threadIdx.x + 256] = 0u;
    __syncthreads();

    int b = p >> 8, ph = (p >> 4) & 15, pw = p & 15;
    int y = threadIdx.x >> 4, x = threadIdx.x & 15;
    int rem = (ph * 16 + y) * 256 + (pw * 16 + x);
    const float* lb = lab + img * LAB_STRIDE;
    int kidx[3];
    for (int c = 0; c < 3; ++c) {
        float vv = lb[(b * 3 + c) * 65536 + rem];
        int best = 0; float bd = 3.4e38f;
        for (int k = 0; k < 8; ++k) {
            float d = vv - cen[c][k];
            float dd = d * d;
            if (dd < bd) { bd = dd; best = k; }
        }
        kidx[c] = best;
    }
    atomicAdd(&hcnt[kidx[0] * 64 + kidx[1] * 8 + kidx[2]], 1u);
    __syncthreads();

    float* dst = img ? ht : hr;
    dst[p * 512 + threadIdx.x] = (float)hcnt[threadIdx.x] * (1.f / 256.f);
    dst[p * 512 + threadIdx.x + 256] = (float)hcnt[threadIdx.x + 256] * (1.f / 256.f);
    if (!img) {   // u0 = ones (split: hi=1.0 bf16, lo=0)
        uh[p * 512 + threadIdx.x] = (short)0x3F80;
        uh[p * 512 + threadIdx.x + 256] = (short)0x3F80;
        ul[p * 512 + threadIdx.x] = 0;
        ul[p * 512 + threadIdx.x + 256] = 0;
    }
}

// dst[p,j] = hist[p,j] / (sum_i src[p,i] K[i,j] + 1e-6), output split hi/lo bf16.
// grid (32 p-tiles of 32, 8 j-tiles of 64), 256 threads (4 waves).
// wave -> (p sub-tile of 16) x (2 j-tiles of 16). acc = Ah*Bh + Ah*Bl + Al*Bh.
__global__ __launch_bounds__(256) void gemm_div_kernel(
        const short* __restrict__ ah_g, const short* __restrict__ al_g,
        const short* __restrict__ bh_g, const short* __restrict__ bl_g,
        const float* __restrict__ hist,
        short* __restrict__ dh_g, short* __restrict__ dl_g) {
    int tid = threadIdx.x;
    int wave = tid >> 6, lane = tid & 63;
    int p_base = blockIdx.x * 32 + (wave & 1) * 16;
    int jt0 = blockIdx.y * 4 + (wave >> 1) * 2;
    int arow = (p_base + (lane & 15)) * 512 + (lane >> 4) * 8;
    floatx4 acc0 = {0.f, 0.f, 0.f, 0.f}, acc1 = {0.f, 0.f, 0.f, 0.f};
    #pragma unroll
    for (int kc = 0; kc < 16; ++kc) {
        int aoff = arow + kc * 32;
        short8 ah = *(const short8*)(ah_g + aoff);
        short8 al = *(const short8*)(al_g + aoff);
        int b0 = ((jt0 * 16 + kc) * 64 + lane) * 8;
        int b1 = (((jt0 + 1) * 16 + kc) * 64 + lane) * 8;
        short8 bh0 = *(const short8*)(bh_g + b0);
        short8 bl0 = *(const short8*)(bl_g + b0);
        short8 bh1 = *(const short8*)(bh_g + b1);
        short8 bl1 = *(const short8*)(bl_g + b1);
        acc0 = __builtin_amdgcn_mfma_f32_16x16x32_bf16(ah, bh0, acc0, 0, 0, 0);
        acc1 = __builtin_amdgcn_mfma_f32_16x16x32_bf16(ah, bh1, acc1, 0, 0, 0);
        acc0 = __builtin_amdgcn_mfma_f32_16x16x32_bf16(ah, bl0, acc0, 0, 0, 0);
        acc1 = __builtin_amdgcn_mfma_f32_16x16x32_bf16(ah, bl1, acc1, 0, 0, 0);
        acc0 = __builtin_amdgcn_mfma_f32_16x16x32_bf16(al, bh0, acc0, 0, 0, 0);
        acc1 = __builtin_amdgcn_mfma_f32_16x16x32_bf16(al, bh1, acc1, 0, 0, 0);
    }
    int pr = p_base + (lane >> 4) * 4;
    int jc0 = jt0 * 16 + (lane & 15);
    int jc1 = (jt0 + 1) * 16 + (lane & 15);
    #pragma unroll
    for (int r = 0; r < 4; ++r) {
        int i0 = (pr + r) * 512 + jc0;
        float d = hist[i0] / (acc0[r] + 1e-6f);
        unsigned h = bf16_rne(d);
        float hf = bf16_to_f((unsigned short)h);
        dh_g[i0] = (short)h;
        dl_g[i0] = (short)bf16_rne(d - hf);
        int i1 = (pr + r) * 512 + jc1;
        d = hist[i1] / (acc1[r] + 1e-6f);
        h = bf16_rne(d);
        hf = bf16_to_f((unsigned short)h);
        dh_g[i1] = (short)h;
        dl_g[i1] = (short)bf16_rne(d - hf);
    }
}

// emd[p] += sum_j (sum_i u[p,i] Kc[i,j]) * v[p,j]  — same GEMM, reduce epilogue.
__global__ __launch_bounds__(256) void emd_gemm_kernel(
        const short* __restrict__ ah_g, const short* __restrict__ al_g,
        const short* __restrict__ bh_g, const short* __restrict__ bl_g,
        const short* __restrict__ vh_g, const short* __restrict__ vl_g,
        float* __restrict__ emd) {
    int tid = threadIdx.x;
    int wave = tid >> 6, lane = tid & 63;
    int p_base = blockIdx.x * 32 + (wave & 1) * 16;
    int jt0 = blockIdx.y * 4 + (wave >> 1) * 2;
    int arow = (p_base + (lane & 15)) * 512 + (lane >> 4) * 8;
    floatx4 acc0 = {0.f, 0.f, 0.f, 0.f}, acc1 = {0.f, 0.f, 0.f, 0.f};
    #pragma unroll
    for (int kc = 0; kc < 16; ++kc) {
        int aoff = arow + kc * 32;
        short8 ah = *(const short8*)(ah_g + aoff);
        short8 al = *(const short8*)(al_g + aoff);
        int b0 = ((jt0 * 16 + kc) * 64 + lane) * 8;
        int b1 = (((jt0 + 1) * 16 + kc) * 64 + lane) * 8;
        short8 bh0 = *(const short8*)(bh_g + b0);
        short8 bl0 = *(const short8*)(bl_g + b0);
        short8 bh1 = *(const short8*)(bh_g + b1);
        short8 bl1 = *(const short8*)(bl_g + b1);
        acc0 = __builtin_amdgcn_mfma_f32_16x16x32_bf16(ah, bh0, acc0, 0, 0, 0);
        acc1 = __builtin_amdgcn_mfma_f32_16x16x32_bf16(ah, bh1, acc1, 0, 0, 0);
        acc0 = __builtin_amdgcn_mfma_f32_16x16x32_bf16(ah, bl0, acc0, 0, 0, 0);
        acc1 = __builtin_amdgcn_mfma_f32_16x16x32_bf16(ah, bl1, acc1, 0, 0, 0);
        acc0 = __builtin_amdgcn_mfma_f32_16x16x32_bf16(al, bh0, acc0, 0, 0, 0);
        acc1 = __builtin_amdgcn_mfma_f32_16x16x32_bf16(al, bh1, acc1, 0, 0, 0);
    }
    __shared__ float es[32];
    if (tid < 32) es[tid] = 0.f;
    __syncthreads();
    int pr = p_base + (lane >> 4) * 4;
    int jc0 = jt0 * 16 + (lane & 15);
    int jc1 = (jt0 + 1) * 16 + (lane & 15);
    #pragma unroll
    for (int r = 0; r < 4; ++r) {
        int i0 = (pr + r) * 512 + jc0;
        int i1 = (pr + r) * 512 + jc1;
        float v0 = bf16_to_f((unsigned short)vh_g[i0]) + bf16_to_f((unsigned short)vl_g[i0]);
        float v1 = bf16_to_f((unsigned short)vh_g[i1]) + bf16_to_f((unsigned short)vl_g[i1]);
        float contrib = acc0[r] * v0 + acc1[r] * v1;
        atomicAdd(&es[pr + r - blockIdx.x * 32], contrib);
    }
    __syncthreads();
    if (tid < 32) atomicAdd(&emd[blockIdx.x * 32 + tid], es[tid]);
}

// (4,1,16,16) -> (4,1,256,256), half-pixel bilinear, edge clamp, nan_to_num
__global__ __launch_bounds__(256) void upsample_kernel(
        const float* __restrict__ emd, float* __restrict__ out) {
    int idx = blockIdx.x * 256 + threadIdx.x;   // 0..262143
    int b = idx >> 16;
    int rem = idx & 65535;
    int y = rem >> 8, x = rem & 255;
    float sy = (y + 0.5f) * 0.0625f - 0.5f;
    float sx = (x + 0.5f) * 0.0625f - 0.5f;
    float fy0 = floorf(sy), fx0 = floorf(sx);
    float fy = sy - fy0, fx = sx - fx0;
    int y0 = (int)fy0, x0 = (int)fx0;
    int y0c = min(max(y0, 0), 15), y1c = min(max(y0 + 1, 0), 15);
    int x0c = min(max(x0, 0), 15), x1c = min(max(x0 + 1, 0), 15);
    const float* e = emd + b * 256;
    float v00 = e[y0c * 16 + x0c], v01 = e[y0c * 16 + x1c];
    float v10 = e[y1c * 16 + x0c], v11 = e[y1c * 16 + x1c];
    if (!__builtin_isfinite(v00)) v00 = 0.f;
    if (!__builtin_isfinite(v01)) v01 = 0.f;
    if (!__builtin_isfinite(v10)) v10 = 0.f;
    if (!__builtin_isfinite(v11)) v11 = 0.f;
    out[idx] = (1.f - fy) * ((1.f - fx) * v00 + fx * v01)
             + fy * ((1.f - fx) * v10 + fx * v11);
}

extern "C" void kernel_launch(void* const* d_in, const int* in_sizes, int n_in,
                              void* d_out, int out_size, void* d_ws, size_t ws_size,
                              hipStream_t stream) {
    const float* ref = (const float*)d_in[0];
    const float* tgt = (const float*)d_in[1];
    float* out = (float*)d_out;

    float* lab = (float*)d_ws;                       // 1572864 f32
    unsigned* mm = (unsigned*)(lab + 2 * LAB_STRIDE); // 16 u32
    float* hr = (float*)(mm + 16);                    // 524288 f32
    float* ht = hr + 524288;                          // 524288 f32
    float* emd = ht + 524288;                         // 1024 f32
    short* uh = (short*)(emd + 1024);                 // 524288 bf16
    short* ul = uh + 524288;
    short* vh = ul + 524288;
    short* vl = vh + 524288;
    short* kmh = vl + 524288;                         // 262144 bf16
    short* kml = kmh + 262144;
    short* kch = kml + 262144;
    short* kcl = kch + 262144;

    init_kernel<<<1, 1024, 0, stream>>>(mm, emd);
    oklab_minmax_kernel<<<1024, 256, 0, stream>>>(ref, tgt, lab, mm);
    pack_k_kernel<<<dim3(32, 16), 64, 0, stream>>>(mm, kmh, kml, kch, kcl);
    hist_kernel<<<2048, 256, 0, stream>>>(lab, mm, hr, ht, uh, ul);

    for (int it = 0; it < 20; ++it) {
        gemm_div_kernel<<<dim3(32, 8), 256, 0, stream>>>(uh, ul, kmh, kml, ht, vh, vl);
        gemm_div_kernel<<<dim3(32, 8), 256, 0, stream>>>(vh, vl, kmh, kml, hr, uh, ul);
    }
    emd_gemm_kernel<<<dim3(32, 8), 256, 0, stream>>>(uh, ul, kch, kcl, vh, vl, emd);
    upsample_kernel<<<1024, 256, 0, stream>>>(emd, out);
}